// Round 1
// baseline (341.881 us; speedup 1.0000x reference)
//
#include <hip/hip_runtime.h>
#include <stdint.h>

#define K_TAGS   32
#define START_IX 30
#define END_IX   31

// CRF forward as a linear recurrence with exact power-of-2 rescaling.
// Mapping: 1 wave (64 lanes) = 2 batches; lane = (batch-half, tag c).
// Per-lane state: u = 2^-off * exp(alpha[c]); E-column in 32 VGPRs.
__global__ __launch_bounds__(64) void crf_fwd_kernel(
    const float* __restrict__ frames,   // [B][T][32]
    const float* __restrict__ trans,    // [32][32] (prev -> cur)
    float* __restrict__ out,            // [B]
    int T)
{
    const int lane = threadIdx.x;       // 0..63
    const int c    = lane & 31;         // tag owned by this lane
    const int half = lane >> 5;         // which batch within the wave
    const int b    = blockIdx.x * 2 + half;

    __shared__ float xbuf[64];          // per-wave exchange buffer (single block = single wave)

    const float L2E = 1.44269504088896340736f;

    // E column for this lane: Ec[p] = exp(trans[p][c]).
    // trans[:,START] = -1e4 -> Ec underflows to exactly 0 for c==START (correct).
    float Ec[32];
#pragma unroll
    for (int p = 0; p < 32; ++p)
        Ec[p] = exp2f(trans[p * 32 + c] * L2E);
    // terminal transition weight: exp(trans[c][END])
    const float Eend = exp2f(trans[c * 32 + END_IX] * L2E);

    // init: alpha0 = 0 at START, -inf elsewhere  ->  u = indicator(START)
    float u   = (c == START_IX) ? 1.0f : 0.0f;
    int   off = 0;           // exact base-2 scale: u_true = u * 2^off

    const float* fp = frames + (size_t)b * T * K_TAGS + c;

    // 4-deep frame prefetch pipeline (hides HBM latency; feeds g off-chain)
    float fq[4];
#pragma unroll
    for (int j = 0; j < 4; ++j) fq[j] = fp[j * K_TAGS];

    float u0s = 1.0f;        // stale broadcast of group's u[c=0] for renorm

    const float4* xv = (const float4*)(xbuf + half * 32);

    for (int t0 = 0; t0 < T; t0 += 4) {
        const bool rn = (t0 & 4) != 0;   // renorm window every 8 steps
#pragma unroll
        for (int j = 0; j < 4; ++j) {
            const int t = t0 + j;
            // g = exp(frame) * 2^-6  (computed from frame loaded 4 steps ago -> off-chain)
            float g = exp2f(fmaf(fq[j], L2E, -6.0f));

            // issue next prefetch early (clamped uniform index; tail reloads last row harmlessly)
            int tn = t + 4; if (tn > T - 1) tn = T - 1;
            float fnew = fp[tn * K_TAGS];

            // --- exchange u across the 32-lane group (wave-synchronous, in-order LDS pipe) ---
            xbuf[lane] = u;
            float4 uv[8];
#pragma unroll
            for (int i = 0; i < 8; ++i) uv[i] = xv[i];   // broadcast reads, conflict-free

            // --- v[c] = sum_p u[p] * E[p][c], 4 accumulator chains ---
            float a0 = 0.f, a1 = 0.f, a2 = 0.f, a3 = 0.f;
#pragma unroll
            for (int i = 0; i < 8; ++i) {
                a0 = fmaf(uv[i].x, Ec[4 * i + 0], a0);
                a1 = fmaf(uv[i].y, Ec[4 * i + 1], a1);
                a2 = fmaf(uv[i].z, Ec[4 * i + 2], a2);
                a3 = fmaf(uv[i].w, Ec[4 * i + 3], a3);
            }
            float v = (a0 + a1) + (a2 + a3);
            u = v * g;

            fq[j] = fnew;

            if (rn && j == 2) {
                // broadcast u of lane c==0 of this group (1-step-stale by the time it's used)
                u0s = __shfl(u, half << 5, 64);
            }
            if (rn && j == 3) {
                // exact power-of-2 renorm: u *= 2^-e, off += e  (no log/exp needed)
                int eb = (int)((__float_as_uint(u0s) >> 23) & 255u) - 127;
                u *= __uint_as_float((uint32_t)(127 - eb) << 23);
                off += eb;
            }
        }
        off += 24;   // the folded 2^-6 per step, 4 steps
    }

    // final: score = ln2 * (off + log2( sum_p u[p] * exp(trans[p][END]) ))
    float w = u * Eend;
#pragma unroll
    for (int m = 1; m <= 16; m <<= 1) w += __shfl_xor(w, m, 64);

    if (c == 0) {
        double res = ((double)off + (double)log2f(w)) * 0.693147180559945309417;
        out[b] = (float)res;
    }
}

extern "C" void kernel_launch(void* const* d_in, const int* in_sizes, int n_in,
                              void* d_out, int out_size, void* d_ws, size_t ws_size,
                              hipStream_t stream)
{
    const float* frames = (const float*)d_in[0];
    const float* trans  = (const float*)d_in[1];
    float* out = (float*)d_out;

    const int B = out_size;                         // 1024
    const int T = in_sizes[0] / (B * K_TAGS);       // 1024

    dim3 grid(B / 2), block(64);
    crf_fwd_kernel<<<grid, block, 0, stream>>>(frames, trans, out, T);
}